// Round 12
// baseline (275.009 us; speedup 1.0000x reference)
//
#include <hip/hip_runtime.h>
#include <hip/hip_bf16.h>
#include <math.h>

// ---------------- workspace layout (float offsets; exact round-8) ---------
static constexpr size_t W1T_OFF  = 0;                // PKB: 57344 floats
static constexpr size_t W2T_OFF  = 62208;            // 1048576 -> end 1110784
static constexpr size_t H_OFF    = 1110784;          // 4718592 -> end 5829376 (bf16)
static constexpr size_t PPART_OFF= 5829376;          // 5308416 -> end 11137792
static constexpr size_t UT_OFF   = 11137792;         // 663552  -> end 11801344  u fp32 [n][b][i]
static constexpr size_t S0_OFF   = 11801344;
static constexpr size_t OUT0_OFF = 11845376;         // OUTT iter0: [c][b][o]
static constexpr size_t S1_OFF   = 11889408;
static constexpr size_t OUT1_OFF = 11933440;
static constexpr size_t S2_OFF   = 11977472;         // -> end 12021504
static constexpr size_t PKW_OFF  = 0;                // 3698688 (bf16 frags; after squash_u)
static constexpr size_t L_OFF    = 3698688;          // 3566592 -> end 7265280
static constexpr size_t PR_OFF   = 7265280;          // 3566592 -> end 10831872

typedef __bf16 bf16x8 __attribute__((ext_vector_type(8)));
typedef float  f32x4  __attribute__((ext_vector_type(4)));

__device__ inline unsigned pk2(float a, float b) {     // packed RNE bf16 pair
    __hip_bfloat162 h = __float22bfloat162_rn(make_float2(a, b));
    return *(unsigned*)&h;
}

// ---------------- init: S0/OUT0/S1/OUT1/S2 <- 0 ---------------------------
__global__ void k_init(float* ws) {
    int g = blockIdx.x * 256 + threadIdx.x;          // 860*256 = 220160 exact
    ws[S0_OFF + g] = 0.f;
}

// ---- pack conv1_w -> bf16 B-frags PKB[((ocq*14+s)*4+nt)*64+lane] ---------
__global__ void k_packb1(float* ws, const float* w1) {
    int g = blockIdx.x * 256 + threadIdx.x;          // 56*256 = 14336 exact
    int lane = g & 63;
    int r = g >> 6;                                  // 224 = 4ocq * 14s * 4nt
    int nt = r & 3, s = (r >> 2) % 14, ocq = r / 56;
    int quad = lane >> 4;
    int oc = ocq * 64 + nt * 16 + (lane & 15);
    int grp = 2 * s + (quad >> 1);
    int kxb = (quad & 1) * 8;
    uint4 o = {0u, 0u, 0u, 0u};
    if (grp < 27) {
        const float* wp = w1 + (size_t)oc * 243 + grp * 9;
        float v[8];
#pragma unroll
        for (int j = 0; j < 8; ++j) {
            int kx = kxb + j;
            v[j] = (kx < 9) ? wp[kx] : 0.f;
        }
        o.x = pk2(v[0], v[1]); o.y = pk2(v[2], v[3]);
        o.z = pk2(v[4], v[5]); o.w = pk2(v[6], v[7]);
    }
    ((uint4*)(ws + W1T_OFF))[g] = o;
}

// ---- pack prim_w (128 x 16384 fp32) -> bf16 MFMA B-fragment order --------
__global__ void k_pack2(float* ws, const float* w2) {
    int g = blockIdx.x * 256 + threadIdx.x;          // 1024 blocks -> 262144 exact
    int s = g >> 9;
    int r = g & 511;
    int nt = r >> 6, lane = r & 63;
    int n = nt * 16 + (lane & 15);
    int k0 = s * 32 + (lane >> 4) * 8;
    const float4* src = (const float4*)(w2 + (size_t)n * 16384 + k0);
    float4 v0 = src[0], v1 = src[1];
    uint4 o;
    o.x = pk2(v0.x, v0.y); o.y = pk2(v0.z, v0.w);
    o.z = pk2(v1.x, v1.y); o.w = pk2(v1.z, v1.w);
    ((uint4*)(ws + W2T_OFF))[g] = o;
}

// ---- pack route_w -> bf16 B-frags PKW[((c*16+tile)*21+ks)*64+lane] -------
__global__ void k_packw(float* ws, const float* rw) {
    int g = blockIdx.x * 256 + threadIdx.x;          // 3612*256 = 924672 exact
    int lane = g & 63;
    int e = g >> 6;                                  // 14448 = 43 * 336
    int c = e / 336;
    int r = e % 336;
    int tile = r / 21, ks = r % 21;
    int quad = lane >> 4, o = lane & 15;
    int nl = ks * 4 + quad;
    uint4 out = {0u, 0u, 0u, 0u};
    if (nl < 81) {
        int n = tile * 81 + nl;
        const float* wp = rw + ((size_t)n * 43 + c) * 128 + o;
        out.x = pk2(wp[0],  wp[16]);
        out.y = pk2(wp[32], wp[48]);
        out.z = pk2(wp[64], wp[80]);
        out.w = pk2(wp[96], wp[112]);
    }
    ((uint4*)(ws + PKW_OFF))[g] = out;
}

// ------------- conv1 as implicit-im2col bf16 MFMA GEMM --------------------
__global__ __launch_bounds__(256, 1) void k_conv1_mfma(float* ws, const float* x,
                                                       const float* b1) {
    __shared__ float xf[3136];
    __shared__ unsigned xd[2][1552];
    int blk = blockIdx.x;
    int b = blk >> 2, ocq = blk & 3;
    int t = threadIdx.x;

    const float4* xg = (const float4*)(x + (size_t)b * 3072);
    float4* xf4 = (float4*)xf;
#pragma unroll
    for (int i = t; i < 784; i += 256)
        xf4[i] = (i < 768) ? xg[i] : make_float4(0.f, 0.f, 0.f, 0.f);
    __syncthreads();
    for (int i = t; i < 1552; i += 256) {
        float a0 = xf[2 * i], a1 = xf[2 * i + 1], a2 = xf[2 * i + 2];
        xd[0][i] = pk2(a0, a1);
        xd[1][i] = pk2(a1, a2);
    }
    __syncthreads();

    int w = t >> 6, lane = t & 63;
    int quad = lane >> 4, mrow = lane & 15;

    f32x4 acc[9][4];
#pragma unroll
    for (int mt = 0; mt < 9; ++mt)
#pragma unroll
        for (int nt = 0; nt < 4; ++nt) acc[mt][nt] = (f32x4){0.f, 0.f, 0.f, 0.f};

    int exo[9];
#pragma unroll
    for (int mt = 0; mt < 9; ++mt) {
        int p = (w * 9 + mt) * 16 + mrow;
        exo[mt] = (p / 24) * 32 + (p % 24) + (quad & 1) * 8;
    }

    const uint4* pkb = (const uint4*)(ws + W1T_OFF) + (size_t)(ocq * 56) * 64;
    int gh = quad >> 1;

    for (int s = 0; s < 14; ++s) {
        int g = 2 * s + gh;
        int goff = (g < 27) ? (g / 9) * 1024 + (g % 9) * 32 : 0;
        uint4 bfr[4];
#pragma unroll
        for (int nt = 0; nt < 4; ++nt) bfr[nt] = pkb[(size_t)(s * 4 + nt) * 64 + lane];
        union { unsigned u[4]; bf16x8 v; } afr[9];
#pragma unroll
        for (int mt = 0; mt < 9; ++mt) {
            int e = goff + exo[mt];
            const unsigned* xp = &xd[e & 1][e >> 1];
            afr[mt].u[0] = xp[0]; afr[mt].u[1] = xp[1];
            afr[mt].u[2] = xp[2]; afr[mt].u[3] = xp[3];
        }
#pragma unroll
        for (int nt = 0; nt < 4; ++nt) {
            union { uint4 u; bf16x8 v; } bv; bv.u = bfr[nt];
#pragma unroll
            for (int mt = 0; mt < 9; ++mt)
                acc[mt][nt] = __builtin_amdgcn_mfma_f32_16x16x32_bf16(
                    afr[mt].v, bv.v, acc[mt][nt], 0, 0, 0);
        }
    }

    unsigned short* hb = (unsigned short*)(ws + H_OFF);
#pragma unroll
    for (int nt = 0; nt < 4; ++nt) {
        int oc = ocq * 64 + nt * 16 + mrow;
        float bias = b1[oc];
        unsigned* hp = (unsigned*)(hb + (size_t)(b * 256 + oc) * 576);
#pragma unroll
        for (int mt = 0; mt < 9; ++mt) {
            int p = (w * 9 + mt) * 16 + quad * 4;
            float v0 = fmaxf(acc[mt][nt][0] + bias, 0.f);
            float v1 = fmaxf(acc[mt][nt][1] + bias, 0.f);
            float v2 = fmaxf(acc[mt][nt][2] + bias, 0.f);
            float v3 = fmaxf(acc[mt][nt][3] + bias, 0.f);
            hp[(p >> 1) + 0] = pk2(v0, v1);
            hp[(p >> 1) + 1] = pk2(v2, v3);
        }
    }
}

// ------------- conv2: N split into quarters, single barrier per stage -----
// grid 2048 = 64 b x 8 kq x 4 nh ; block 256 = 4 waves (mg=M-half, ng=N-tile)
// 8 blocks/CU co-resident; K-order unchanged -> bit-identical partials.
__global__ __launch_bounds__(256, 8) void k_conv2_mfma(float* ws) {
    __shared__ unsigned short hs[2][2304];           // 2 bufs x 4ch x 576
    int blk = blockIdx.x;
    int b  = blk >> 5;
    int kq = (blk >> 2) & 7;
    int nh = blk & 3;
    int t = threadIdx.x;
    int w = t >> 6, lane = t & 63;
    int quad = lane >> 4, m = lane & 15;
    int mg = w >> 1, ng = w & 1;

    int aoy2[3], aox[3];
#pragma unroll
    for (int mi = 0; mi < 3; ++mi) {
        int p = (mg * 3 + mi) * 16 + m;
        if (p > 80) p = 0;
        aoy2[mi] = (p / 9) * 2;
        aox[mi] = p % 9;
    }

    const float4* hsg = (const float4*)((const unsigned short*)(ws + H_OFF)
                         + (size_t)(b * 256 + kq * 32) * 576);
    const uint4* wp = (const uint4*)(ws + W2T_OFF);
    int ntb = nh * 2 + ng;                           // this wave's N-tile (16 oc)

    f32x4 acc[3];
#pragma unroll
    for (int mi = 0; mi < 3; ++mi) acc[mi] = (f32x4){0.f, 0.f, 0.f, 0.f};

    auto bidx = [&](int st, int cL, int ks) -> size_t {
        int s = (kq * 32 + st * 4 + cL) * 2 + ks;
        return (size_t)(s * 8 + ntb) * 64 + lane;
    };

    ((float4*)&hs[0][0])[t] = hsg[t];
    if (t < 32) ((float4*)&hs[0][0])[256 + t] = hsg[256 + t];
    uint4 bc0 = wp[bidx(0, 0, 0)], bc1 = wp[bidx(0, 0, 1)];
    __syncthreads();

    for (int st = 0; st < 8; ++st) {
        float4 pre0, pre1;
        bool more = (st < 7);
        if (more) {
            pre0 = hsg[(st + 1) * 288 + t];
            if (t < 32) pre1 = hsg[(st + 1) * 288 + 256 + t];
        }
        const unsigned short* buf = &hs[st & 1][0];
#pragma unroll
        for (int cL = 0; cL < 4; ++cL) {
            int nst = (cL < 3) ? st : st + 1;
            int ncl = (cL < 3) ? cL + 1 : 0;
            bool pf = (nst < 8);
            uint4 bn0, bn1;
            if (pf) {
                bn0 = wp[bidx(nst, ncl, 0)];
                bn1 = wp[bidx(nst, ncl, 1)];
            }
            const unsigned short* cbuf = buf + cL * 576;
#pragma unroll
            for (int ks = 0; ks < 2; ++ks) {
                union { uint4 u; bf16x8 v; } bf;
                bf.u = ks ? bc1 : bc0;
                int rowk = ks * 4 + quad;
#pragma unroll
                for (int mi = 0; mi < 3; ++mi) {
                    const unsigned int* ap =
                        (const unsigned int*)cbuf + (aoy2[mi] + rowk) * 12 + aox[mi];
                    union { unsigned int u[4]; bf16x8 v; } af;
                    af.u[0] = ap[0]; af.u[1] = ap[1]; af.u[2] = ap[2]; af.u[3] = ap[3];
                    acc[mi] = __builtin_amdgcn_mfma_f32_16x16x32_bf16(
                        af.v, bf.v, acc[mi], 0, 0, 0);
                }
            }
            if (pf) { bc0 = bn0; bc1 = bn1; }
        }
        // write next stage into the buffer last read in stage st-1 (safe:
        // all waves passed the st-1 end-barrier; stage-st reads use buf[st&1])
        if (more) {
            ((float4*)&hs[(st + 1) & 1][0])[t] = pre0;
            if (t < 32) ((float4*)&hs[(st + 1) & 1][0])[256 + t] = pre1;
        }
        __syncthreads();
    }

    float* pp = ws + PPART_OFF + ((size_t)(kq * 64 + b) * 81) * 128;
#pragma unroll
    for (int mi = 0; mi < 3; ++mi) {
        int n = ntb * 16 + m;
#pragma unroll
        for (int reg = 0; reg < 4; ++reg) {
            int p = (mg * 3 + mi) * 16 + quad * 4 + reg;
            if (p < 81) pp[(size_t)p * 128 + n] = acc[mi][reg];
        }
    }
}

// ------- squash: sum 8 kq partials + bias -> u fp32 [n][b][i] -------------
__global__ void k_squash_u(float* ws, const float* prim_b) {
    __shared__ float vs[128];
    __shared__ float fac[16];
    int blk = blockIdx.x;
    int b = blk / 81, s = blk % 81;
    int n = threadIdx.x;
    const float* pp = ws + PPART_OFF;
    float v = prim_b[n];
#pragma unroll
    for (int kq = 0; kq < 8; ++kq)
        v += pp[((size_t)(kq * 64 + b) * 81 + s) * 128 + n];
    vs[n] = v;
    __syncthreads();
    if (n < 16) {
        float sn = 0.f;
#pragma unroll
        for (int i = 0; i < 8; ++i) { float tv = vs[i * 16 + n]; sn += tv * tv; }
        fac[n] = sqrtf(sn) / (1.f + sn);
    }
    __syncthreads();
    int i = n >> 4, d = n & 15;
    ws[UT_OFF + ((size_t)(d * 81 + s) * 64 + b) * 8 + i] = v * fac[d];
}

// ------- s accumulation as MFMA GEMM (round-8 atomic version) -------------
__global__ __launch_bounds__(256) void k_saccum_mfma(float* ws, const float* probs,
                                                     float* sdst) {
    int bx = blockIdx.x;
    int c = bx % 43, tile = bx / 43;
    int n0 = tile * 81;
    int t = threadIdx.x;
    int w = t >> 6, lane = t & 63;
    int quad = lane >> 4, m = lane & 15;
    int b = w * 16 + m;
    const float* ut = ws + UT_OFF;
    const uint4* pkw = (const uint4*)(ws + PKW_OFF)
                       + ((size_t)(c * 16 + tile) * 21) * 64 + lane;
    f32x4 acc = {0.f, 0.f, 0.f, 0.f};
#pragma unroll 7
    for (int ks = 0; ks < 21; ++ks) {
        int nl = ks * 4 + quad;
        union { uint4 u; bf16x8 v; } bf;
        bf.u = pkw[(size_t)ks * 64];
        union { unsigned u[4]; bf16x8 v; } af;
        af.u[0] = af.u[1] = af.u[2] = af.u[3] = 0u;
        if (nl < 81) {
            int n = n0 + nl;
            const float4* up = (const float4*)(ut + ((size_t)n * 64 + b) * 8);
            float4 u0 = up[0], u1 = up[1];
            float pv = probs ? probs[((size_t)n * 43 + c) * 64 + b] : 1.0f;
            af.u[0] = pk2(u0.x * pv, u0.y * pv);
            af.u[1] = pk2(u0.z * pv, u0.w * pv);
            af.u[2] = pk2(u1.x * pv, u1.y * pv);
            af.u[3] = pk2(u1.z * pv, u1.w * pv);
        }
        acc = __builtin_amdgcn_mfma_f32_16x16x32_bf16(af.v, bf.v, acc, 0, 0, 0);
    }
#pragma unroll
    for (int reg = 0; reg < 4; ++reg) {
        int bo = w * 16 + quad * 4 + reg;
        atomicAdd(sdst + ((size_t)bo * 43 + c) * 16 + m, acc[reg]);
    }
}

// -------- outputs = squash(s * scale), written transposed OUTT[c][b][o] ---
__global__ void k_outsquash(const float* s, float* ot, float scale) {
    int g = blockIdx.x * 256 + threadIdx.x;          // 11 blocks, 2752 tasks
    if (g >= 2752) return;
    int b = g / 43, c = g % 43;
    const float4* sp = (const float4*)(s + (size_t)g * 16);
    float v[16]; float sn = 0.f;
#pragma unroll
    for (int q = 0; q < 4; ++q) {
        float4 w = sp[q];
        v[q * 4] = w.x * scale; v[q * 4 + 1] = w.y * scale;
        v[q * 4 + 2] = w.z * scale; v[q * 4 + 3] = w.w * scale;
    }
#pragma unroll
    for (int j = 0; j < 16; ++j) sn += v[j] * v[j];
    float f = sqrtf(sn) / (1.f + sn);
    float4* op = (float4*)(ot + ((size_t)c * 64 + b) * 16);
#pragma unroll
    for (int q = 0; q < 4; ++q)
        op[q] = make_float4(v[q*4] * f, v[q*4+1] * f, v[q*4+2] * f, v[q*4+3] * f);
}

// ---- delta via MFMA + FUSED softmax --------------------------------------
__global__ __launch_bounds__(256) void k_delta_mfma(float* ws, const float* outt,
                                                    float* L, float* P, int add) {
    __shared__ float ls[2752];                       // 43c x 64b updated logits
    int n = blockIdx.x, t = threadIdx.x;
    int w = t >> 6, lane = t & 63;
    int quad = lane >> 4, col = lane & 15;
    int b = w * 16 + col;

    union { unsigned u[4]; bf16x8 v; } bfrag;
    bfrag.u[0] = bfrag.u[1] = bfrag.u[2] = bfrag.u[3] = 0u;
    if (quad == 0) {
        const float4* up = (const float4*)(ws + UT_OFF + ((size_t)n * 64 + b) * 8);
        float4 u0 = up[0], u1 = up[1];
        bfrag.u[0] = pk2(u0.x, u0.y); bfrag.u[1] = pk2(u0.z, u0.w);
        bfrag.u[2] = pk2(u1.x, u1.y); bfrag.u[3] = pk2(u1.z, u1.w);
    }

    int tile = n / 81, nl = n % 81;
    int ks = nl >> 2, qpk = nl & 3;
    const uint4* pkw = (const uint4*)(ws + PKW_OFF);
    size_t abase = ((size_t)tile * 21 + ks) * 64 + qpk * 16 + col;
    const float4* ot4 = (const float4*)outt;
    size_t obase = (size_t)b * 4 + quad;

    uint4 a_cur = pkw[abase];
    float4 o_cur = ot4[obase];
    for (int c = 0; c < 43; ++c) {
        uint4 a_nxt; float4 o_nxt;
        if (c < 42) {
            a_nxt = pkw[abase + (size_t)(c + 1) * 21504];
            o_nxt = ot4[obase + (size_t)(c + 1) * 256];
        }
        union { uint4 u; bf16x8 v; } afrag; afrag.u = a_cur;
        f32x4 zero = {0.f, 0.f, 0.f, 0.f};
        f32x4 acc = __builtin_amdgcn_mfma_f32_16x16x32_bf16(afrag.v, bfrag.v, zero, 0, 0, 0);
        float val = acc[0] * o_cur.x + acc[1] * o_cur.y
                  + acc[2] * o_cur.z + acc[3] * o_cur.w;
        val += __shfl_xor(val, 16);
        val += __shfl_xor(val, 32);
        if (quad == 0) {
            size_t idx = ((size_t)n * 43 + c) * 64 + b;
            float nv;
            if (add) {
                nv = L[idx] + val;                   // final iter: L write is dead
            } else {
                nv = val;
                L[idx] = nv;                         // persisted for next delta
            }
            ls[c * 64 + b] = nv;
        }
        a_cur = a_nxt; o_cur = o_nxt;
    }

    __syncthreads();
    if (t < 64) {                                    // per-b softmax over c
        int bb = t;
        float m = -1e30f;
#pragma unroll
        for (int c = 0; c < 43; ++c) m = fmaxf(m, ls[c * 64 + bb]);
        float ssum = 0.f;
#pragma unroll
        for (int c = 0; c < 43; ++c) {
            float e = __expf(ls[c * 64 + bb] - m);
            ls[c * 64 + bb] = e;
            ssum += e;
        }
        float inv = 1.f / ssum;
        float* pp = P + (size_t)n * 2752 + bb;
#pragma unroll
        for (int c = 0; c < 43; ++c) pp[c * 64] = ls[c * 64 + bb] * inv;
    }
}

// ---------------- scores[b,c] = ||squash(s2)|| = sn/(1+sn) ----------------
__global__ void k_scores(const float* s2, float* out) {
    int g = blockIdx.x * 256 + threadIdx.x;
    if (g >= 2752) return;
    const float4* sp = (const float4*)(s2 + (size_t)g * 16);
    float sn = 0.f;
#pragma unroll
    for (int q = 0; q < 4; ++q) {
        float4 w = sp[q];
        sn += w.x * w.x + w.y * w.y + w.z * w.z + w.w * w.w;
    }
    out[g] = sn / (1.f + sn);
}

extern "C" void kernel_launch(void* const* d_in, const int* in_sizes, int n_in,
                              void* d_out, int out_size, void* d_ws, size_t ws_size,
                              hipStream_t stream) {
    const float* x  = (const float*)d_in[0];
    const float* w1 = (const float*)d_in[1];
    const float* b1 = (const float*)d_in[2];
    const float* w2 = (const float*)d_in[3];
    const float* b2 = (const float*)d_in[4];
    const float* rw = (const float*)d_in[5];
    float* ws  = (float*)d_ws;
    float* out = (float*)d_out;

    k_init      <<<860,  256, 0, stream>>>(ws);
    k_packb1    <<<56,   256, 0, stream>>>(ws, w1);
    k_pack2     <<<1024, 256, 0, stream>>>(ws, w2);
    k_conv1_mfma<<<256,  256, 0, stream>>>(ws, x, b1);
    k_conv2_mfma<<<2048, 256, 0, stream>>>(ws);
    k_squash_u  <<<5184, 128, 0, stream>>>(ws, b2);
    k_packw     <<<3612, 256, 0, stream>>>(ws, rw);   // overwrites PKB/W2T/H-head (dead)
    // iter 0: uniform probs (1/43 folded into squash scale)
    k_saccum_mfma<<<688, 256, 0, stream>>>(ws, nullptr, ws + S0_OFF);
    k_outsquash <<<11,  256, 0, stream>>>(ws + S0_OFF, ws + OUT0_OFF, 1.0f / 43.0f);
    k_delta_mfma<<<1296,256, 0, stream>>>(ws, ws + OUT0_OFF, ws + L_OFF, ws + PR_OFF, 0);
    // iter 1
    k_saccum_mfma<<<688, 256, 0, stream>>>(ws, ws + PR_OFF, ws + S1_OFF);
    k_outsquash <<<11,  256, 0, stream>>>(ws + S1_OFF, ws + OUT1_OFF, 1.0f);
    k_delta_mfma<<<1296,256, 0, stream>>>(ws, ws + OUT1_OFF, ws + L_OFF, ws + PR_OFF, 1);
    // iter 2
    k_saccum_mfma<<<688, 256, 0, stream>>>(ws, ws + PR_OFF, ws + S2_OFF);
    k_scores    <<<11,  256, 0, stream>>>(ws + S2_OFF, out);
}

// Round 13
// 254.193 us; speedup vs baseline: 1.0819x; 1.0819x over previous
//
#include <hip/hip_runtime.h>
#include <hip/hip_bf16.h>
#include <math.h>

// ---------------- workspace layout (float offsets; exact round-8) ---------
static constexpr size_t W1T_OFF  = 0;                // PKB: 57344 floats
static constexpr size_t W2T_OFF  = 62208;            // 1048576 -> end 1110784
static constexpr size_t H_OFF    = 1110784;          // 4718592 -> end 5829376 (bf16)
static constexpr size_t PPART_OFF= 5829376;          // 5308416 -> end 11137792
static constexpr size_t UT_OFF   = 11137792;         // 663552  -> end 11801344  u fp32 [n][b][i]
static constexpr size_t S0_OFF   = 11801344;
static constexpr size_t OUT0_OFF = 11845376;         // OUTT iter0: [c][b][o]
static constexpr size_t S1_OFF   = 11889408;
static constexpr size_t OUT1_OFF = 11933440;
static constexpr size_t S2_OFF   = 11977472;         // -> end 12021504
static constexpr size_t PKW_OFF  = 0;                // 3698688 (bf16 frags; after squash_u)
static constexpr size_t L_OFF    = 3698688;          // 3566592 -> end 7265280
static constexpr size_t PR_OFF   = 7265280;          // 3566592 -> end 10831872

typedef __bf16 bf16x8 __attribute__((ext_vector_type(8)));
typedef float  f32x4  __attribute__((ext_vector_type(4)));

__device__ inline unsigned pk2(float a, float b) {     // packed RNE bf16 pair
    __hip_bfloat162 h = __float22bfloat162_rn(make_float2(a, b));
    return *(unsigned*)&h;
}

// ---------------- init: S0/OUT0/S1/OUT1/S2 <- 0 ---------------------------
__global__ void k_init(float* ws) {
    int g = blockIdx.x * 256 + threadIdx.x;          // 860*256 = 220160 exact
    ws[S0_OFF + g] = 0.f;
}

// ---- pack conv1_w -> bf16 B-frags PKB[((ocq*14+s)*4+nt)*64+lane] ---------
__global__ void k_packb1(float* ws, const float* w1) {
    int g = blockIdx.x * 256 + threadIdx.x;          // 56*256 = 14336 exact
    int lane = g & 63;
    int r = g >> 6;                                  // 224 = 4ocq * 14s * 4nt
    int nt = r & 3, s = (r >> 2) % 14, ocq = r / 56;
    int quad = lane >> 4;
    int oc = ocq * 64 + nt * 16 + (lane & 15);
    int grp = 2 * s + (quad >> 1);
    int kxb = (quad & 1) * 8;
    uint4 o = {0u, 0u, 0u, 0u};
    if (grp < 27) {
        const float* wp = w1 + (size_t)oc * 243 + grp * 9;
        float v[8];
#pragma unroll
        for (int j = 0; j < 8; ++j) {
            int kx = kxb + j;
            v[j] = (kx < 9) ? wp[kx] : 0.f;
        }
        o.x = pk2(v[0], v[1]); o.y = pk2(v[2], v[3]);
        o.z = pk2(v[4], v[5]); o.w = pk2(v[6], v[7]);
    }
    ((uint4*)(ws + W1T_OFF))[g] = o;
}

// ---- pack prim_w (128 x 16384 fp32) -> bf16 MFMA B-fragment order --------
__global__ void k_pack2(float* ws, const float* w2) {
    int g = blockIdx.x * 256 + threadIdx.x;          // 1024 blocks -> 262144 exact
    int s = g >> 9;
    int r = g & 511;
    int nt = r >> 6, lane = r & 63;
    int n = nt * 16 + (lane & 15);
    int k0 = s * 32 + (lane >> 4) * 8;
    const float4* src = (const float4*)(w2 + (size_t)n * 16384 + k0);
    float4 v0 = src[0], v1 = src[1];
    uint4 o;
    o.x = pk2(v0.x, v0.y); o.y = pk2(v0.z, v0.w);
    o.z = pk2(v1.x, v1.y); o.w = pk2(v1.z, v1.w);
    ((uint4*)(ws + W2T_OFF))[g] = o;
}

// ---- pack route_w -> bf16 B-frags PKW[((c*16+tile)*21+ks)*64+lane] -------
__global__ void k_packw(float* ws, const float* rw) {
    int g = blockIdx.x * 256 + threadIdx.x;          // 3612*256 = 924672 exact
    int lane = g & 63;
    int e = g >> 6;                                  // 14448 = 43 * 336
    int c = e / 336;
    int r = e % 336;
    int tile = r / 21, ks = r % 21;
    int quad = lane >> 4, o = lane & 15;
    int nl = ks * 4 + quad;
    uint4 out = {0u, 0u, 0u, 0u};
    if (nl < 81) {
        int n = tile * 81 + nl;
        const float* wp = rw + ((size_t)n * 43 + c) * 128 + o;
        out.x = pk2(wp[0],  wp[16]);
        out.y = pk2(wp[32], wp[48]);
        out.z = pk2(wp[64], wp[80]);
        out.w = pk2(wp[96], wp[112]);
    }
    ((uint4*)(ws + PKW_OFF))[g] = out;
}

// ------------- conv1 as implicit-im2col bf16 MFMA GEMM --------------------
__global__ __launch_bounds__(256, 1) void k_conv1_mfma(float* ws, const float* x,
                                                       const float* b1) {
    __shared__ float xf[3136];
    __shared__ unsigned xd[2][1552];
    int blk = blockIdx.x;
    int b = blk >> 2, ocq = blk & 3;
    int t = threadIdx.x;

    const float4* xg = (const float4*)(x + (size_t)b * 3072);
    float4* xf4 = (float4*)xf;
#pragma unroll
    for (int i = t; i < 784; i += 256)
        xf4[i] = (i < 768) ? xg[i] : make_float4(0.f, 0.f, 0.f, 0.f);
    __syncthreads();
    for (int i = t; i < 1552; i += 256) {
        float a0 = xf[2 * i], a1 = xf[2 * i + 1], a2 = xf[2 * i + 2];
        xd[0][i] = pk2(a0, a1);
        xd[1][i] = pk2(a1, a2);
    }
    __syncthreads();

    int w = t >> 6, lane = t & 63;
    int quad = lane >> 4, mrow = lane & 15;

    f32x4 acc[9][4];
#pragma unroll
    for (int mt = 0; mt < 9; ++mt)
#pragma unroll
        for (int nt = 0; nt < 4; ++nt) acc[mt][nt] = (f32x4){0.f, 0.f, 0.f, 0.f};

    int exo[9];
#pragma unroll
    for (int mt = 0; mt < 9; ++mt) {
        int p = (w * 9 + mt) * 16 + mrow;
        exo[mt] = (p / 24) * 32 + (p % 24) + (quad & 1) * 8;
    }

    const uint4* pkb = (const uint4*)(ws + W1T_OFF) + (size_t)(ocq * 56) * 64;
    int gh = quad >> 1;

    for (int s = 0; s < 14; ++s) {
        int g = 2 * s + gh;
        int goff = (g < 27) ? (g / 9) * 1024 + (g % 9) * 32 : 0;
        uint4 bfr[4];
#pragma unroll
        for (int nt = 0; nt < 4; ++nt) bfr[nt] = pkb[(size_t)(s * 4 + nt) * 64 + lane];
        union { unsigned u[4]; bf16x8 v; } afr[9];
#pragma unroll
        for (int mt = 0; mt < 9; ++mt) {
            int e = goff + exo[mt];
            const unsigned* xp = &xd[e & 1][e >> 1];
            afr[mt].u[0] = xp[0]; afr[mt].u[1] = xp[1];
            afr[mt].u[2] = xp[2]; afr[mt].u[3] = xp[3];
        }
#pragma unroll
        for (int nt = 0; nt < 4; ++nt) {
            union { uint4 u; bf16x8 v; } bv; bv.u = bfr[nt];
#pragma unroll
            for (int mt = 0; mt < 9; ++mt)
                acc[mt][nt] = __builtin_amdgcn_mfma_f32_16x16x32_bf16(
                    afr[mt].v, bv.v, acc[mt][nt], 0, 0, 0);
        }
    }

    unsigned short* hb = (unsigned short*)(ws + H_OFF);
#pragma unroll
    for (int nt = 0; nt < 4; ++nt) {
        int oc = ocq * 64 + nt * 16 + mrow;
        float bias = b1[oc];
        unsigned* hp = (unsigned*)(hb + (size_t)(b * 256 + oc) * 576);
#pragma unroll
        for (int mt = 0; mt < 9; ++mt) {
            int p = (w * 9 + mt) * 16 + quad * 4;
            float v0 = fmaxf(acc[mt][nt][0] + bias, 0.f);
            float v1 = fmaxf(acc[mt][nt][1] + bias, 0.f);
            float v2 = fmaxf(acc[mt][nt][2] + bias, 0.f);
            float v3 = fmaxf(acc[mt][nt][3] + bias, 0.f);
            hp[(p >> 1) + 0] = pk2(v0, v1);
            hp[(p >> 1) + 1] = pk2(v2, v3);
        }
    }
}

// ------------- conv2 as implicit-im2col bf16 MFMA GEMM --------------------
// grid 1024 = 64 b x 8 kq x 2 nh (round-8/11 shape); single barrier/stage:
// the write into hs[(st+1)&1] targets the buffer read in stage st-1, and the
// stage-(st-1) end barrier already ordered those reads before this write.
__global__ __launch_bounds__(256, 4) void k_conv2_mfma(float* ws) {
    __shared__ unsigned short hs[2][2304];           // 2 bufs x 4ch x 576
    int blk = blockIdx.x;
    int b  = blk >> 4;
    int kq = (blk >> 1) & 7;
    int nh = blk & 1;
    int t = threadIdx.x;
    int w = t >> 6, lane = t & 63;
    int quad = lane >> 4, m = lane & 15;
    int mg = w >> 1, ng = w & 1;

    int aoy2[3], aox[3];
#pragma unroll
    for (int mi = 0; mi < 3; ++mi) {
        int p = (mg * 3 + mi) * 16 + m;
        if (p > 80) p = 0;
        aoy2[mi] = (p / 9) * 2;
        aox[mi] = p % 9;
    }

    const float4* hsg = (const float4*)((const unsigned short*)(ws + H_OFF)
                         + (size_t)(b * 256 + kq * 32) * 576);
    const uint4* wp = (const uint4*)(ws + W2T_OFF);
    int ntb = nh * 4 + ng * 2;

    f32x4 acc[3][2];
#pragma unroll
    for (int mi = 0; mi < 3; ++mi)
#pragma unroll
        for (int ni = 0; ni < 2; ++ni) acc[mi][ni] = (f32x4){0.f, 0.f, 0.f, 0.f};

    auto bidx = [&](int st, int cL, int ks, int ni) -> size_t {
        int s = (kq * 32 + st * 4 + cL) * 2 + ks;
        return (size_t)(s * 8 + ntb + ni) * 64 + lane;
    };

    ((float4*)&hs[0][0])[t] = hsg[t];
    if (t < 32) ((float4*)&hs[0][0])[256 + t] = hsg[256 + t];
    uint4 bc0 = wp[bidx(0, 0, 0, 0)], bc1 = wp[bidx(0, 0, 0, 1)];
    uint4 bc2 = wp[bidx(0, 0, 1, 0)], bc3 = wp[bidx(0, 0, 1, 1)];
    __syncthreads();

    for (int st = 0; st < 8; ++st) {
        float4 pre0, pre1;
        bool more = (st < 7);
        if (more) {
            pre0 = hsg[(st + 1) * 288 + t];
            if (t < 32) pre1 = hsg[(st + 1) * 288 + 256 + t];
        }
        const unsigned short* buf = &hs[st & 1][0];
#pragma unroll
        for (int cL = 0; cL < 4; ++cL) {
            int nst = (cL < 3) ? st : st + 1;
            int ncl = (cL < 3) ? cL + 1 : 0;
            bool pf = (nst < 8);
            uint4 bn0, bn1, bn2, bn3;
            if (pf) {
                bn0 = wp[bidx(nst, ncl, 0, 0)]; bn1 = wp[bidx(nst, ncl, 0, 1)];
                bn2 = wp[bidx(nst, ncl, 1, 0)]; bn3 = wp[bidx(nst, ncl, 1, 1)];
            }
            const unsigned short* cbuf = buf + cL * 576;
#pragma unroll
            for (int ks = 0; ks < 2; ++ks) {
                union { uint4 u; bf16x8 v; } bf0, bf1;
                bf0.u = ks ? bc2 : bc0;
                bf1.u = ks ? bc3 : bc1;
                int rowk = ks * 4 + quad;
#pragma unroll
                for (int mi = 0; mi < 3; ++mi) {
                    const unsigned int* ap =
                        (const unsigned int*)cbuf + (aoy2[mi] + rowk) * 12 + aox[mi];
                    union { unsigned int u[4]; bf16x8 v; } af;
                    af.u[0] = ap[0]; af.u[1] = ap[1]; af.u[2] = ap[2]; af.u[3] = ap[3];
                    acc[mi][0] = __builtin_amdgcn_mfma_f32_16x16x32_bf16(
                        af.v, bf0.v, acc[mi][0], 0, 0, 0);
                    acc[mi][1] = __builtin_amdgcn_mfma_f32_16x16x32_bf16(
                        af.v, bf1.v, acc[mi][1], 0, 0, 0);
                }
            }
            if (pf) { bc0 = bn0; bc1 = bn1; bc2 = bn2; bc3 = bn3; }
        }
        // single barrier per stage: write into the buffer last read at st-1
        if (more) {
            ((float4*)&hs[(st + 1) & 1][0])[t] = pre0;
            if (t < 32) ((float4*)&hs[(st + 1) & 1][0])[256 + t] = pre1;
        }
        __syncthreads();
    }

    float* pp = ws + PPART_OFF + ((size_t)(kq * 64 + b) * 81) * 128;
#pragma unroll
    for (int mi = 0; mi < 3; ++mi) {
#pragma unroll
        for (int ni = 0; ni < 2; ++ni) {
            int n = nh * 64 + (ng * 2 + ni) * 16 + m;
#pragma unroll
            for (int reg = 0; reg < 4; ++reg) {
                int p = (mg * 3 + mi) * 16 + quad * 4 + reg;
                if (p < 81) pp[(size_t)p * 128 + n] = acc[mi][ni][reg];
            }
        }
    }
}

// ------- squash: sum 8 kq partials + bias -> u fp32 [n][b][i] -------------
__global__ void k_squash_u(float* ws, const float* prim_b) {
    __shared__ float vs[128];
    __shared__ float fac[16];
    int blk = blockIdx.x;
    int b = blk / 81, s = blk % 81;
    int n = threadIdx.x;
    const float* pp = ws + PPART_OFF;
    float v = prim_b[n];
#pragma unroll
    for (int kq = 0; kq < 8; ++kq)
        v += pp[((size_t)(kq * 64 + b) * 81 + s) * 128 + n];
    vs[n] = v;
    __syncthreads();
    if (n < 16) {
        float sn = 0.f;
#pragma unroll
        for (int i = 0; i < 8; ++i) { float tv = vs[i * 16 + n]; sn += tv * tv; }
        fac[n] = sqrtf(sn) / (1.f + sn);
    }
    __syncthreads();
    int i = n >> 4, d = n & 15;
    ws[UT_OFF + ((size_t)(d * 81 + s) * 64 + b) * 8 + i] = v * fac[d];
}

// ------- s accumulation as MFMA GEMM (round-8 atomic version) -------------
__global__ __launch_bounds__(256) void k_saccum_mfma(float* ws, const float* probs,
                                                     float* sdst) {
    int bx = blockIdx.x;
    int c = bx % 43, tile = bx / 43;
    int n0 = tile * 81;
    int t = threadIdx.x;
    int w = t >> 6, lane = t & 63;
    int quad = lane >> 4, m = lane & 15;
    int b = w * 16 + m;
    const float* ut = ws + UT_OFF;
    const uint4* pkw = (const uint4*)(ws + PKW_OFF)
                       + ((size_t)(c * 16 + tile) * 21) * 64 + lane;
    f32x4 acc = {0.f, 0.f, 0.f, 0.f};
#pragma unroll 7
    for (int ks = 0; ks < 21; ++ks) {
        int nl = ks * 4 + quad;
        union { uint4 u; bf16x8 v; } bf;
        bf.u = pkw[(size_t)ks * 64];
        union { unsigned u[4]; bf16x8 v; } af;
        af.u[0] = af.u[1] = af.u[2] = af.u[3] = 0u;
        if (nl < 81) {
            int n = n0 + nl;
            const float4* up = (const float4*)(ut + ((size_t)n * 64 + b) * 8);
            float4 u0 = up[0], u1 = up[1];
            float pv = probs ? probs[((size_t)n * 43 + c) * 64 + b] : 1.0f;
            af.u[0] = pk2(u0.x * pv, u0.y * pv);
            af.u[1] = pk2(u0.z * pv, u0.w * pv);
            af.u[2] = pk2(u1.x * pv, u1.y * pv);
            af.u[3] = pk2(u1.z * pv, u1.w * pv);
        }
        acc = __builtin_amdgcn_mfma_f32_16x16x32_bf16(af.v, bf.v, acc, 0, 0, 0);
    }
#pragma unroll
    for (int reg = 0; reg < 4; ++reg) {
        int bo = w * 16 + quad * 4 + reg;
        atomicAdd(sdst + ((size_t)bo * 43 + c) * 16 + m, acc[reg]);
    }
}

// -------- outputs = squash(s * scale), written transposed OUTT[c][b][o] ---
__global__ void k_outsquash(const float* s, float* ot, float scale) {
    int g = blockIdx.x * 256 + threadIdx.x;          // 11 blocks, 2752 tasks
    if (g >= 2752) return;
    int b = g / 43, c = g % 43;
    const float4* sp = (const float4*)(s + (size_t)g * 16);
    float v[16]; float sn = 0.f;
#pragma unroll
    for (int q = 0; q < 4; ++q) {
        float4 w = sp[q];
        v[q * 4] = w.x * scale; v[q * 4 + 1] = w.y * scale;
        v[q * 4 + 2] = w.z * scale; v[q * 4 + 3] = w.w * scale;
    }
#pragma unroll
    for (int j = 0; j < 16; ++j) sn += v[j] * v[j];
    float f = sqrtf(sn) / (1.f + sn);
    float4* op = (float4*)(ot + ((size_t)c * 64 + b) * 16);
#pragma unroll
    for (int q = 0; q < 4; ++q)
        op[q] = make_float4(v[q*4] * f, v[q*4+1] * f, v[q*4+2] * f, v[q*4+3] * f);
}

// ---- delta via MFMA + FUSED softmax --------------------------------------
__global__ __launch_bounds__(256) void k_delta_mfma(float* ws, const float* outt,
                                                    float* L, float* P, int add) {
    __shared__ float ls[2752];                       // 43c x 64b updated logits
    int n = blockIdx.x, t = threadIdx.x;
    int w = t >> 6, lane = t & 63;
    int quad = lane >> 4, col = lane & 15;
    int b = w * 16 + col;

    union { unsigned u[4]; bf16x8 v; } bfrag;
    bfrag.u[0] = bfrag.u[1] = bfrag.u[2] = bfrag.u[3] = 0u;
    if (quad == 0) {
        const float4* up = (const float4*)(ws + UT_OFF + ((size_t)n * 64 + b) * 8);
        float4 u0 = up[0], u1 = up[1];
        bfrag.u[0] = pk2(u0.x, u0.y); bfrag.u[1] = pk2(u0.z, u0.w);
        bfrag.u[2] = pk2(u1.x, u1.y); bfrag.u[3] = pk2(u1.z, u1.w);
    }

    int tile = n / 81, nl = n % 81;
    int ks = nl >> 2, qpk = nl & 3;
    const uint4* pkw = (const uint4*)(ws + PKW_OFF);
    size_t abase = ((size_t)tile * 21 + ks) * 64 + qpk * 16 + col;
    const float4* ot4 = (const float4*)outt;
    size_t obase = (size_t)b * 4 + quad;

    uint4 a_cur = pkw[abase];
    float4 o_cur = ot4[obase];
    for (int c = 0; c < 43; ++c) {
        uint4 a_nxt; float4 o_nxt;
        if (c < 42) {
            a_nxt = pkw[abase + (size_t)(c + 1) * 21504];
            o_nxt = ot4[obase + (size_t)(c + 1) * 256];
        }
        union { uint4 u; bf16x8 v; } afrag; afrag.u = a_cur;
        f32x4 zero = {0.f, 0.f, 0.f, 0.f};
        f32x4 acc = __builtin_amdgcn_mfma_f32_16x16x32_bf16(afrag.v, bfrag.v, zero, 0, 0, 0);
        float val = acc[0] * o_cur.x + acc[1] * o_cur.y
                  + acc[2] * o_cur.z + acc[3] * o_cur.w;
        val += __shfl_xor(val, 16);
        val += __shfl_xor(val, 32);
        if (quad == 0) {
            size_t idx = ((size_t)n * 43 + c) * 64 + b;
            float nv;
            if (add) {
                nv = L[idx] + val;                   // final iter: L write is dead
            } else {
                nv = val;
                L[idx] = nv;                         // persisted for next delta
            }
            ls[c * 64 + b] = nv;
        }
        a_cur = a_nxt; o_cur = o_nxt;
    }

    __syncthreads();
    if (t < 64) {                                    // per-b softmax over c
        int bb = t;
        float m = -1e30f;
#pragma unroll
        for (int c = 0; c < 43; ++c) m = fmaxf(m, ls[c * 64 + bb]);
        float ssum = 0.f;
#pragma unroll
        for (int c = 0; c < 43; ++c) {
            float e = __expf(ls[c * 64 + bb] - m);
            ls[c * 64 + bb] = e;
            ssum += e;
        }
        float inv = 1.f / ssum;
        float* pp = P + (size_t)n * 2752 + bb;
#pragma unroll
        for (int c = 0; c < 43; ++c) pp[c * 64] = ls[c * 64 + bb] * inv;
    }
}

// ---------------- scores[b,c] = ||squash(s2)|| = sn/(1+sn) ----------------
__global__ void k_scores(const float* s2, float* out) {
    int g = blockIdx.x * 256 + threadIdx.x;
    if (g >= 2752) return;
    const float4* sp = (const float4*)(s2 + (size_t)g * 16);
    float sn = 0.f;
#pragma unroll
    for (int q = 0; q < 4; ++q) {
        float4 w = sp[q];
        sn += w.x * w.x + w.y * w.y + w.z * w.z + w.w * w.w;
    }
    out[g] = sn / (1.f + sn);
}

extern "C" void kernel_launch(void* const* d_in, const int* in_sizes, int n_in,
                              void* d_out, int out_size, void* d_ws, size_t ws_size,
                              hipStream_t stream) {
    const float* x  = (const float*)d_in[0];
    const float* w1 = (const float*)d_in[1];
    const float* b1 = (const float*)d_in[2];
    const float* w2 = (const float*)d_in[3];
    const float* b2 = (const float*)d_in[4];
    const float* rw = (const float*)d_in[5];
    float* ws  = (float*)d_ws;
    float* out = (float*)d_out;

    k_init      <<<860,  256, 0, stream>>>(ws);
    k_packb1    <<<56,   256, 0, stream>>>(ws, w1);
    k_pack2     <<<1024, 256, 0, stream>>>(ws, w2);
    k_conv1_mfma<<<256,  256, 0, stream>>>(ws, x, b1);
    k_conv2_mfma<<<1024, 256, 0, stream>>>(ws);
    k_squash_u  <<<5184, 128, 0, stream>>>(ws, b2);
    k_packw     <<<3612, 256, 0, stream>>>(ws, rw);   // overwrites PKB/W2T/H-head (dead)
    // iter 0: uniform probs (1/43 folded into squash scale)
    k_saccum_mfma<<<688, 256, 0, stream>>>(ws, nullptr, ws + S0_OFF);
    k_outsquash <<<11,  256, 0, stream>>>(ws + S0_OFF, ws + OUT0_OFF, 1.0f / 43.0f);
    k_delta_mfma<<<1296,256, 0, stream>>>(ws, ws + OUT0_OFF, ws + L_OFF, ws + PR_OFF, 0);
    // iter 1
    k_saccum_mfma<<<688, 256, 0, stream>>>(ws, ws + PR_OFF, ws + S1_OFF);
    k_outsquash <<<11,  256, 0, stream>>>(ws + S1_OFF, ws + OUT1_OFF, 1.0f);
    k_delta_mfma<<<1296,256, 0, stream>>>(ws, ws + OUT1_OFF, ws + L_OFF, ws + PR_OFF, 1);
    // iter 2
    k_saccum_mfma<<<688, 256, 0, stream>>>(ws, ws + PR_OFF, ws + S2_OFF);
    k_scores    <<<11,  256, 0, stream>>>(ws + S2_OFF, out);
}